// Round 3
// baseline (137.058 us; speedup 1.0000x reference)
//
#include <hip/hip_runtime.h>
#include <cmath>

#define Bz 4
#define Tz 1000
#define Wz 32
#define Dz 200
#define EDz 400
#define Nz 16
#define DTRz 13
#define Lz 1001
#define POSz 500
#define LPz 501
#define TSTR 512
#define NEG_BIG -1e30f

__device__ __forceinline__ float wave_sum(float v) {
#pragma unroll
  for (int o = 32; o; o >>= 1) v += __shfl_xor(v, o);
  return v;
}

// grid = 9 + Bz*Tz blocks.
// blocks 0..8: setup (v[e], CLS row -> xn[POS], z). blocks 9..: word-pool.
__global__ __launch_bounds__(256) void k_front(
    const float* __restrict__ x, const int* __restrict__ n_tweets,
    const int* __restrict__ n_words, const float* __restrict__ w_attn,
    const float* __restrict__ b_attn, const float* __restrict__ norm_w,
    const float* __restrict__ cls, const float* __restrict__ out_proj,
    const float* __restrict__ head_w, const float* __restrict__ ipf,
    const float* __restrict__ ipb, float* __restrict__ xn,
    float* __restrict__ zbuf, float* __restrict__ vbuf) {
  int bid = blockIdx.x;
  int tid = threadIdx.x;
  if (bid < 9) {
    if (bid == 0) {
      __shared__ float hw[Dz];
      if (tid < Dz) hw[tid] = head_w[tid];
      __syncthreads();
      for (int e = tid; e < EDz; e += 256) {
        float acc = 0.f;
        for (int d = 0; d < Dz; d += 4) {
          float4 ov = *(const float4*)(out_proj + e * Dz + d);
          acc += ov.x * hw[d] + ov.y * hw[d + 1] + ov.z * hw[d + 2] + ov.w * hw[d + 3];
        }
        vbuf[e] = acc;
      }
      return;
    }
    int id = bid - 1;
    int br = id >> 2, b = id & 3;
    __shared__ float xs[Dz];
    __shared__ float s_red[4];
    float val = (tid < Dz) ? cls[tid] : 0.f;
    float sq = wave_sum(val * val);
    if ((tid & 63) == 0) s_red[tid >> 6] = sq;
    __syncthreads();
    float tot = s_red[0] + s_red[1] + s_red[2] + s_red[3];
    float scale = rsqrtf(tot * (1.f / Dz) + 1e-5f);
    if (tid < Dz) {
      float o = val * scale * norm_w[tid];
      xs[tid] = o;
      if (br == 0) xn[((size_t)b * Lz + POSz) * Dz + tid] = o;
    }
    __syncthreads();
    const float* ip = br ? ipb : ipf;
    for (int e = tid; e < EDz; e += 256) {
      float acc = 0.f;
      for (int d = 0; d < Dz; ++d) acc += xs[d] * ip[d * (2 * EDz) + EDz + e];
      zbuf[((size_t)br * Bz + b) * EDz + e] = acc;
    }
    return;
  }
  // ---- pool ----
  int blk = bid - 9;
  int b = blk / Tz, t = blk - b * Tz;
  int l = (t < POSz) ? t : t + 1;
  float* outp = xn + ((size_t)b * Lz + l) * Dz;
  int ntw = n_tweets[b]; if (ntw > Tz) ntw = Tz;
  if (t >= ntw) { if (tid < Dz) outp[tid] = 0.f; return; }
  int nw = n_words[b * Tz + t]; if (nw > Wz) nw = Wz; if (nw < 1) nw = 1;
  const float* xs = x + ((size_t)(b * Tz + t)) * (Wz * Dz);
  __shared__ float s_attn[Wz];
  __shared__ float s_red[4];
  int w = tid >> 3, j = tid & 7;
  float sc = 0.f;
  if (w < nw) {
    for (int d = j * 4; d < Dz; d += 32) {
      float4 xv = *(const float4*)(xs + w * Dz + d);
      float4 wv = *(const float4*)(w_attn + d);
      sc += xv.x * wv.x + xv.y * wv.y + xv.z * wv.z + xv.w * wv.w;
    }
  }
  sc += __shfl_xor(sc, 1); sc += __shfl_xor(sc, 2); sc += __shfl_xor(sc, 4);
  if (j == 0) s_attn[w] = (w < nw) ? (sc + b_attn[0]) : NEG_BIG;
  __syncthreads();
  if (tid < 64) {
    float s = (tid < Wz) ? s_attn[tid] : NEG_BIG;
    float m = s;
#pragma unroll
    for (int o = 32; o; o >>= 1) m = fmaxf(m, __shfl_xor(m, o));
    float e = (s > 0.5f * NEG_BIG) ? __expf(s - m) : 0.f;
    float tot = wave_sum(e);
    if (tid < Wz) s_attn[tid] = e / tot;
  }
  __syncthreads();
  float val = 0.f;
  if (tid < Dz) {
    for (int ww = 0; ww < nw; ++ww) val += s_attn[ww] * xs[ww * Dz + tid];
  }
  float sq = wave_sum(val * val);
  if ((tid & 63) == 0) s_red[tid >> 6] = sq;
  __syncthreads();
  float tot = s_red[0] + s_red[1] + s_red[2] + s_red[3];
  float scale = rsqrtf(tot * (1.f / Dz) + 1e-5f);
  if (tid < Dz) outp[tid] = val * scale * norm_w[tid];
}

// Fused in_proj (wave-uniform s_load X) -> conv+silu -> xproj -> dt.
// Transposed padded outputs: xp_t/dt_t [brb][e][TSTR], Bm_t [brb][n][TSTR].
__global__ __launch_bounds__(512) void k_fused(
    const float* __restrict__ xn,
    const float* __restrict__ ipf, const float* __restrict__ ipb,
    const float* __restrict__ cwf, const float* __restrict__ cwb,
    const float* __restrict__ cbf, const float* __restrict__ cbb,
    const float* __restrict__ xpjf, const float* __restrict__ xpjb,
    const float* __restrict__ dtwf, const float* __restrict__ dtwb,
    const float* __restrict__ dtbf, const float* __restrict__ dtbb,
    float* __restrict__ xp_t, float* __restrict__ dt_t,
    float* __restrict__ Bm_t, float* __restrict__ Cend) {
  int blk = blockIdx.x;
  int br = blk / (Bz * 63);
  int rem = blk - br * (Bz * 63);
  int b = rem / 63, tile = rem - b * 63;
  int t0 = tile * 8;
  int tid = threadIdx.x;
  const float* ip = br ? ipb : ipf;
  const float* cw = br ? cwb : cwf;
  const float* cb = br ? cbb : cbf;
  const float* xpj = br ? xpjb : xpjf;
  const float* dtw = br ? dtwb : dtwf;
  const float* dtb = br ? dtbb : dtbf;

  __shared__ float sx[8 * EDz];
  __shared__ float sdbc[8][45];

  size_t cbase = (size_t)(br * Bz + b) * EDz * TSTR;

  if (tid < EDz) {
    int e = tid;
    const float* xr[11];
    float msk[11];
#pragma unroll
    for (int r = 0; r < 11; ++r) {
      int lt = t0 - 3 + r;
      bool ok = (lt >= 0 && lt < LPz);
      int ltc = ok ? lt : 0;
      int l = br ? (Lz - 1 - ltc) : ltc;
      xr[r] = xn + ((size_t)b * Lz + l) * Dz;
      msk[r] = ok ? 1.f : 0.f;
    }
    float acc[11];
#pragma unroll
    for (int r = 0; r < 11; ++r) acc[r] = 0.f;
    for (int d = 0; d < Dz; d += 4) {
      float w0 = ip[(size_t)(d + 0) * (2 * EDz) + e];
      float w1 = ip[(size_t)(d + 1) * (2 * EDz) + e];
      float w2 = ip[(size_t)(d + 2) * (2 * EDz) + e];
      float w3 = ip[(size_t)(d + 3) * (2 * EDz) + e];
#pragma unroll
      for (int r = 0; r < 11; ++r) {
        float4 xv = *(const float4*)(xr[r] + d);  // wave-uniform -> s_load
        acc[r] += xv.x * w0 + xv.y * w1 + xv.z * w2 + xv.w * w3;
      }
    }
#pragma unroll
    for (int r = 0; r < 11; ++r) acc[r] *= msk[r];
    float4 c4 = *(const float4*)(cw + e * 4);
    float cbv = cb[e];
    float outv[8];
#pragma unroll
    for (int r = 0; r < 8; ++r) {
      float a = cbv + c4.x * acc[r] + c4.y * acc[r + 1] + c4.z * acc[r + 2] +
                c4.w * acc[r + 3];
      float sp = a / (1.f + __expf(-a));
      outv[r] = sp;
      sx[r * EDz + e] = sp;
    }
    float* xpp = xp_t + cbase + (size_t)e * TSTR + t0;
    *(float4*)(xpp) = make_float4(outv[0], outv[1], outv[2], outv[3]);
    *(float4*)(xpp + 4) = make_float4(outv[4], outv[5], outv[6], outv[7]);
  }
  __syncthreads();
  if (tid < 360) {
    int q = tid >> 3, p = tid & 7;  // q: output col (45), p: e-partial
    float accp[8];
#pragma unroll
    for (int r = 0; r < 8; ++r) accp[r] = 0.f;
    for (int k = 0; k < 13; ++k) {
      int e0 = k * 32 + p * 4;
      if (e0 < EDz) {
        float w0 = xpj[(size_t)(e0 + 0) * 45 + q];
        float w1 = xpj[(size_t)(e0 + 1) * 45 + q];
        float w2 = xpj[(size_t)(e0 + 2) * 45 + q];
        float w3 = xpj[(size_t)(e0 + 3) * 45 + q];
#pragma unroll
        for (int r = 0; r < 8; ++r) {
          float4 s4 = *(const float4*)(sx + r * EDz + e0);
          accp[r] += s4.x * w0 + s4.y * w1 + s4.z * w2 + s4.w * w3;
        }
      }
    }
#pragma unroll
    for (int r = 0; r < 8; ++r) {
      float v = accp[r];
      v += __shfl_xor(v, 1); v += __shfl_xor(v, 2); v += __shfl_xor(v, 4);
      if (p == 0) sdbc[r][q] = v;
    }
  }
  __syncthreads();
  if (tid < EDz) {
    int e = tid;
    float w13[DTRz];
#pragma unroll
    for (int jj = 0; jj < DTRz; ++jj) w13[jj] = dtw[jj * EDz + e];
    float dtbv = dtb[e];
    float outv[8];
#pragma unroll
    for (int r = 0; r < 8; ++r) {
      float s = dtbv;
#pragma unroll
      for (int jj = 0; jj < DTRz; ++jj) s += sdbc[r][jj] * w13[jj];
      outv[r] = (s > 20.f) ? s : log1pf(__expf(s));
    }
    float* dtp = dt_t + cbase + (size_t)e * TSTR + t0;
    *(float4*)(dtp) = make_float4(outv[0], outv[1], outv[2], outv[3]);
    *(float4*)(dtp + 4) = make_float4(outv[4], outv[5], outv[6], outv[7]);
  }
  if (tid >= 384) {
    int q2 = tid - 384;  // 128 threads
    int r = q2 >> 4, n = q2 & 15;
    int t = t0 + r;
    Bm_t[((size_t)(br * Bz + b) * Nz + n) * TSTR + t] = sdbc[r][13 + n];
    if (t == LPz - 1) Cend[(br * Bz + b) * Nz + n] = sdbc[r][29 + n];
  }
}

// h[end,e,n] = sum_t exp(A_n*(Stot-S_t))*dt_t*Bm[t,n]*xp_t, lane-contiguous.
__global__ __launch_bounds__(64) void k_scan(
    const float* __restrict__ xp_t, const float* __restrict__ dt_t,
    const float* __restrict__ Bm_t, const float* __restrict__ Cend,
    const float* __restrict__ Alogf, const float* __restrict__ Alogb,
    const float* __restrict__ Dpf, const float* __restrict__ Dpb,
    const float* __restrict__ zbuf, const float* __restrict__ vbuf,
    float* __restrict__ ybuf) {
  int blk = blockIdx.x;
  int br = blk / (Bz * EDz);
  int rem = blk - br * (Bz * EDz);
  int b = rem / EDz, e = rem - b * EDz;
  int lane = threadIdx.x;
  const float* A_log = br ? Alogb : Alogf;
  const float* Dp = br ? Dpb : Dpf;
  float A[Nz];
  {
    const float4* ap = (const float4*)(A_log + e * Nz);
#pragma unroll
    for (int q = 0; q < 4; ++q) {
      float4 a4 = ap[q];
      A[q * 4 + 0] = -__expf(a4.x); A[q * 4 + 1] = -__expf(a4.y);
      A[q * 4 + 2] = -__expf(a4.z); A[q * 4 + 3] = -__expf(a4.w);
    }
  }
  size_t base = ((size_t)(br * Bz + b) * EDz + e) * TSTR;
  const float* dtp = dt_t + base;
  const float* xpp = xp_t + base;
  const float* bmp = Bm_t + (size_t)(br * Bz + b) * Nz * TSTR;
  float loc = 0.f;
#pragma unroll
  for (int c = 0; c < 8; ++c) {
    int t = c * 64 + lane;
    if (t < LPz) loc += dtp[t];
  }
  float Stot = wave_sum(loc);
  float acc[Nz];
#pragma unroll
  for (int n = 0; n < Nz; ++n) acc[n] = 0.f;
  float carry = 0.f;
  for (int c = 0; c < 8; ++c) {
    int t = c * 64 + lane;
    bool act = t < LPz;
    float dtt = 0.f, xv = 0.f;
    if (act) { dtt = dtp[t]; xv = xpp[t]; }
    float s = dtt;
#pragma unroll
    for (int o = 1; o < 64; o <<= 1) {
      float u = __shfl_up(s, o);
      s += (lane >= o) ? u : 0.f;
    }
    float S = carry + s;
    carry += __shfl(s, 63);
    float wt = dtt * xv;
    float decay = Stot - S;  // >= 0, A<0 => exp<=1
#pragma unroll
    for (int n = 0; n < Nz; ++n) {
      float bv = 0.f;
      if (act) bv = bmp[n * TSTR + t];
      acc[n] += __expf(A[n] * decay) * wt * bv;
    }
  }
#pragma unroll
  for (int o = 32; o; o >>= 1) {
#pragma unroll
    for (int n = 0; n < Nz; ++n) acc[n] += __shfl_xor(acc[n], o);
  }
  if (lane == 0) {
    float y = Dp[e] * xpp[LPz - 1];
#pragma unroll
    for (int n = 0; n < Nz; ++n) y += Cend[(br * Bz + b) * Nz + n] * acc[n];
    float zz = zbuf[((size_t)br * Bz + b) * EDz + e];
    float sz = zz / (1.f + __expf(-zz));
    ybuf[((size_t)br * Bz + b) * EDz + e] = y * sz * vbuf[e];
  }
}

__global__ __launch_bounds__(256) void k_final(
    const float* __restrict__ cls, const float* __restrict__ head_w,
    const float* __restrict__ head_b, const float* __restrict__ ybuf,
    float* __restrict__ out) {
  int tid = threadIdx.x;
  int b = tid >> 6, lane = tid & 63;
  float acc = 0.f;
  for (int e = lane; e < EDz; e += 64)
    acc += ybuf[(size_t)b * EDz + e] + ybuf[(size_t)(Bz + b) * EDz + e];
  for (int d = lane; d < Dz; d += 64) acc += cls[d] * head_w[d];
  acc = wave_sum(acc);
  if (lane == 0) out[b] = 1.f / (1.f + __expf(-(acc + head_b[0])));
}

extern "C" void kernel_launch(void* const* d_in, const int* in_sizes, int n_in,
                              void* d_out, int out_size, void* d_ws, size_t ws_size,
                              hipStream_t stream) {
  const float* input_ids = (const float*)d_in[0];
  const int* n_tweets = (const int*)d_in[1];
  const int* n_words = (const int*)d_in[2];
  const float* cls = (const float*)d_in[3];
  const float* w_attn = (const float*)d_in[4];
  const float* b_attn = (const float*)d_in[5];
  const float* norm_w = (const float*)d_in[6];
  const float* ip[2] = {(const float*)d_in[7], (const float*)d_in[15]};
  const float* cw[2] = {(const float*)d_in[8], (const float*)d_in[16]};
  const float* cb[2] = {(const float*)d_in[9], (const float*)d_in[17]};
  const float* xpj[2] = {(const float*)d_in[10], (const float*)d_in[18]};
  const float* dtw[2] = {(const float*)d_in[11], (const float*)d_in[19]};
  const float* dtbp[2] = {(const float*)d_in[12], (const float*)d_in[20]};
  const float* Alog[2] = {(const float*)d_in[13], (const float*)d_in[21]};
  const float* Dpp[2] = {(const float*)d_in[14], (const float*)d_in[22]};
  const float* out_proj = (const float*)d_in[23];
  const float* head_w = (const float*)d_in[24];
  const float* head_b = (const float*)d_in[25];
  float* out = (float*)d_out;

  float* ws = (float*)d_ws;
  float* xn = ws;                           // 800800
  float* xp_t = xn + 800800;                // 2*4*400*512 = 1638400
  float* dt_t = xp_t + 1638400;             // 1638400
  float* Bm_t = dt_t + 1638400;             // 2*4*16*512 = 65536
  float* Cend = Bm_t + 65536;               // 128
  float* zbuf = Cend + 128;                 // 3200
  float* vbuf = zbuf + 3200;                // 400
  float* ybuf = vbuf + 400;                 // 3200
  // total ~4.15M floats ~16.6 MB

  hipLaunchKernelGGL(k_front, dim3(9 + Bz * Tz), dim3(256), 0, stream,
                     input_ids, n_tweets, n_words, w_attn, b_attn, norm_w,
                     cls, out_proj, head_w, ip[0], ip[1], xn, zbuf, vbuf);
  hipLaunchKernelGGL(k_fused, dim3(2 * Bz * 63), dim3(512), 0, stream,
                     xn, ip[0], ip[1], cw[0], cw[1], cb[0], cb[1],
                     xpj[0], xpj[1], dtw[0], dtw[1], dtbp[0], dtbp[1],
                     xp_t, dt_t, Bm_t, Cend);
  hipLaunchKernelGGL(k_scan, dim3(2 * Bz * EDz), dim3(64), 0, stream,
                     xp_t, dt_t, Bm_t, Cend, Alog[0], Alog[1], Dpp[0], Dpp[1],
                     zbuf, vbuf, ybuf);
  hipLaunchKernelGGL(k_final, dim3(1), dim3(256), 0, stream,
                     cls, head_w, head_b, ybuf, out);
}